// Round 15
// baseline (10236.234 us; speedup 1.0000x reference)
//
#include <hip/hip_runtime.h>
#include <hip/hip_bf16.h>
#include <hip/hip_fp16.h>

#define NN 50000
#define NE 800000
#define NP 50176          // 196*256 padded node count for scan
#define NBLK 196

__device__ __forceinline__ float us2f_bf16(unsigned short u){
    unsigned v = ((unsigned)u) << 16; float f; __builtin_memcpy(&f, &v, 4); return f;
}
__device__ __forceinline__ float us2f_f16(unsigned short u){
    __half h; __builtin_memcpy(&h, &u, 2); return __half2float(h);
}
// mode: 0=bf16, 1=f16, 2=fp32
__device__ __forceinline__ float ldf3(const void* p, size_t i, int mode){
    if (mode == 2) return ((const float*)p)[i];
    unsigned short u = ((const unsigned short*)p)[i];
    return (mode == 0) ? us2f_bf16(u) : us2f_f16(u);
}
__device__ __forceinline__ int ldi(const int* p, size_t j, int i64){
    return i64 ? p[2*j] : p[j];
}

// ---------------- sentinel fill (fp32 output) ----------------
__global__ void fill_k(float* __restrict__ out, int n, float cval){
    int i = blockIdx.x*256 + threadIdx.x;
    if (i < n) out[i] = cval;
}

// ---------------- probes (validated) ----------------
__global__ void probe_f_k(const unsigned short* __restrict__ hf, int* __restrict__ flags){
    __shared__ int cnt;
    if (threadIdx.x == 0) cnt = 0;
    __syncthreads();
    int c = 0;
    for (int idx = threadIdx.x; idx < 2048; idx += 256){
        int ex = (hf[2*idx] >> 7) & 0xFF;
        if (ex >= 118 && ex <= 131) c++;
    }
    atomicAdd(&cnt, c);
    __syncthreads();
    if (threadIdx.x == 0){
        int inb = cnt;
        int mode;
        if (inb >= 1536)      mode = 0;     // bf16
        else if (inb <= 205)  mode = 2;     // fp32
        else                  mode = 1;     // f16
        flags[0] = mode;
    }
}
__global__ void probe_i_k(const int* __restrict__ d, int* __restrict__ flags){
    __shared__ int nz;
    if (threadIdx.x == 0) nz = 0;
    __syncthreads();
    int c = 0;
    for (int idx = threadIdx.x; idx < 2048; idx += 256){
        if (d[2*idx + 1] != 0) c++;
    }
    atomicAdd(&nz, c);
    __syncthreads();
    if (threadIdx.x == 0) flags[1] = (nz < 100) ? 1 : 0;
}

// ---------------- weight conversion ----------------
__global__ void cvt_k(const void* __restrict__ src, float* __restrict__ dst, int n,
                      const int* __restrict__ flags){
    int m = flags[0];
    int i = blockIdx.x*256 + threadIdx.x;
    if (i < n) dst[i] = ldf3(src, i, m);
}

// ---------------- node embedding: wave per node (validated) ----------------
__global__ __launch_bounds__(256) void embed_k(const void* __restrict__ hf,
        const float* __restrict__ W, const float* __restrict__ b,
        float* __restrict__ h, const int* __restrict__ flags){
    int f = flags[0];
    int t = threadIdx.x, c = t & 63;
    int i = blockIdx.x*4 + (t >> 6);
    float a = b[c];
    #pragma unroll
    for (int k=0;k<6;k++) a += ldf3(hf, (size_t)i*6+k, f) * W[k*64+c];
    h[(size_t)i*64+c] = a;
}

// ---------------- CSR build (counting sort by dst, validated) ----------------
__global__ void zero_cnt_k(int* __restrict__ cnt){
    int i = blockIdx.x*256 + threadIdx.x;
    cnt[i] = 0;
}
__global__ void hist_k(const int* __restrict__ dst, int* __restrict__ cnt,
                       const int* __restrict__ flags){
    int i64 = flags[1];
    int j = blockIdx.x*256 + threadIdx.x;
    atomicAdd(&cnt[ldi(dst, j, i64)], 1);
}
__global__ void scan1_k(const int* __restrict__ cnt, int* __restrict__ row_start,
                        int* __restrict__ bsum){
    __shared__ int s[256];
    int t = threadIdx.x;
    int i = blockIdx.x*256 + t;
    int v = cnt[i];
    s[t] = v; __syncthreads();
    #pragma unroll
    for (int off=1; off<256; off<<=1){
        int add = (t>=off) ? s[t-off] : 0;
        __syncthreads();
        s[t] += add;
        __syncthreads();
    }
    row_start[i] = s[t] - v;
    if (t==255) bsum[blockIdx.x] = s[255];
}
__global__ void scan2_k(const int* __restrict__ bsum, int* __restrict__ boff){
    __shared__ int s[256];
    int t = threadIdx.x;
    int v = (t < NBLK) ? bsum[t] : 0;
    s[t] = v; __syncthreads();
    #pragma unroll
    for (int off=1; off<256; off<<=1){
        int add = (t>=off) ? s[t-off] : 0;
        __syncthreads();
        s[t] += add;
        __syncthreads();
    }
    if (t < NBLK) boff[t] = s[t] - v;
}
__global__ void scan3_k(int* __restrict__ row_start, const int* __restrict__ boff,
                        int* __restrict__ cursor){
    int i = blockIdx.x*256 + threadIdx.x;
    int x = row_start[i] + boff[blockIdx.x];
    row_start[i] = x;
    cursor[i] = x;
}
__global__ void scatter_k(const int* __restrict__ dst, int* __restrict__ cursor,
                          int* __restrict__ perm, const int* __restrict__ flags){
    int i64 = flags[1];
    int j = blockIdx.x*256 + threadIdx.x;
    int d = ldi(dst, j, i64);
    int p = atomicAdd(&cursor[d], 1);
    perm[p] = j;
}
// CSR-ordered src: removes the perm->src pointer chase from the hot loop
__global__ void permsrc_k(const int* __restrict__ src, const int* __restrict__ perm,
                          int* __restrict__ srcp, const int* __restrict__ flags){
    int i64 = flags[1];
    int p = blockIdx.x*256 + threadIdx.x;
    srcp[p] = ldi(src, perm[p], i64);
}

// ---------------- e init in CSR order ----------------
__global__ void einit_k(const void* __restrict__ ef, const float* __restrict__ Wee,
                        const float* __restrict__ bee, const int* __restrict__ perm,
                        float* __restrict__ e, const int* __restrict__ flags){
    int f = flags[0];
    int tid = blockIdx.x*256 + threadIdx.x;
    int c = tid & 63, p = tid >> 6;
    int j = perm[p];
    float f0 = ldf3(ef, (size_t)j*2+0, f), f1 = ldf3(ef, (size_t)j*2+1, f);
    e[(size_t)p*64+c] = bee[c] + f0*Wee[c] + f1*Wee[64+c];
}

// ---------------- per-layer Bh, Eh tables: wave per node (validated) ----------
__global__ __launch_bounds__(256) void node2_k(int l, const float* __restrict__ h,
        const float* __restrict__ Wlc, const float* __restrict__ blc,
        float* __restrict__ Bh, float* __restrict__ Eh){
    int t = threadIdx.x, c = t & 63;
    int i = blockIdx.x*4 + (t >> 6);
    const float* WB = Wlc + (size_t)l*5*4096 + 4096;
    const float* WE = Wlc + (size_t)l*5*4096 + 3*4096;
    const float* bm = blc + (size_t)l*320;
    float hv = h[(size_t)i*64 + c];
    float bo = bm[64+c], eo = bm[192+c];
    #pragma unroll 8
    for (int k=0;k<64;k++){
        float hk = __shfl(hv, k);
        bo += hk * WB[k*64+c];
        eo += hk * WE[k*64+c];
    }
    Bh[(size_t)i*64+c] = bo;
    Eh[(size_t)i*64+c] = eo;
}

// ---------------- fused gather: wave per dst node ----------------
// WC staged in LDS (shared per block); e rows read via wave-uniform float4
// broadcasts straight from global (L1-resident within a tile); srcp gives
// sequential src ids. num/den in registers; h update fused.
__global__ __launch_bounds__(256) void gather_k(int l,
        float* __restrict__ e, float* __restrict__ h,
        const float* __restrict__ Bh, const float* __restrict__ Eh,
        const int* __restrict__ srcp,
        const int* __restrict__ row_start,
        const float* __restrict__ Wlc, const float* __restrict__ blc){
    __shared__ float WCs[4096];
    int t = threadIdx.x, c = t & 63, wq = t >> 6;
    int i = blockIdx.x*4 + wq;
    const float* WA = Wlc + (size_t)l*5*4096;
    const float* WD = WA + 2*4096;
    const float* WC = WA + 4*4096;
    const float* bm = blc + (size_t)l*320;
    for (int idx=t; idx<4096; idx+=256) WCs[idx] = WC[idx];
    __syncthreads();

    float hv = h[(size_t)i*64 + c];
    float ah = bm[c], dh = bm[128+c];
    #pragma unroll 8
    for (int k=0;k<64;k++){
        float hk = __shfl(hv, k);
        ah += hk * WA[k*64+c];
        dh += hk * WD[k*64+c];
    }
    float bcv = bm[256+c] + dh;     // bias_C + (Dh_i + bias_D) folded

    int p0 = row_start[i], p1 = row_start[i+1];
    float num = 0.0f, den = 0.0f;

    for (int p=p0; p<p1; p+=8){
        int nv = p1 - p; if (nv > 8) nv = 8;
        const float* rp[8];
        #pragma unroll
        for (int u=0;u<8;u++){
            int ru = (u < nv) ? (p+u) : p0;   // clamp tail to a valid row
            rp[u] = e + (size_t)ru*64;
        }
        float ce[8];
        #pragma unroll
        for (int u=0;u<8;u++) ce[u] = bcv;
        #pragma unroll
        for (int k=0;k<64;k+=4){
            float w0 = WCs[(k+0)*64+c];
            float w1 = WCs[(k+1)*64+c];
            float w2 = WCs[(k+2)*64+c];
            float w3 = WCs[(k+3)*64+c];
            #pragma unroll
            for (int u=0;u<8;u++){
                float4 v = *(const float4*)(rp[u] + k);   // wave-uniform broadcast
                ce[u] = fmaf(v.x, w0, ce[u]);
                ce[u] = fmaf(v.y, w1, ce[u]);
                ce[u] = fmaf(v.z, w2, ce[u]);
                ce[u] = fmaf(v.w, w3, ce[u]);
            }
        }
        #pragma unroll
        for (int u=0;u<8;u++){
            if (u < nv){
                int s = srcp[p+u];
                float ehat = ce[u] + Eh[(size_t)s*64 + c];
                float sig = 1.0f/(1.0f + __expf(-ehat));
                num += sig * Bh[(size_t)s*64 + c];
                den += sig;
                float evc = e[(size_t)(p+u)*64 + c];
                e[(size_t)(p+u)*64 + c] = evc + fmaxf(ehat, 0.0f);
            }
        }
    }
    h[(size_t)i*64 + c] = hv + fmaxf(ah + num/(den + 1e-6f), 0.0f);
}

// ---------------- MLP head: wave per node (validated) ----------------
__global__ __launch_bounds__(256) void head_k(const float* __restrict__ h,
        const float* __restrict__ W1, const float* __restrict__ b1,
        const float* __restrict__ W2, const float* __restrict__ b2,
        float* __restrict__ out){
    int t = threadIdx.x, c = t & 63;
    int i = blockIdx.x*4 + (t >> 6);
    float hv = h[(size_t)i*64 + c];
    float z0 = b1[c], z1 = b1[64+c];
    #pragma unroll 8
    for (int k=0;k<64;k++){
        float hk = __shfl(hv, k);
        z0 += hk * W1[k*128+c];
        z1 += hk * W1[k*128+64+c];
    }
    z0 = fmaxf(z0, 0.0f); z1 = fmaxf(z1, 0.0f);
    float o0 = z0*W2[c*2+0] + z1*W2[(64+c)*2+0];
    float o1 = z0*W2[c*2+1] + z1*W2[(64+c)*2+1];
    #pragma unroll
    for (int off=32; off; off>>=1){
        o0 += __shfl_xor(o0, off);
        o1 += __shfl_xor(o1, off);
    }
    if (c == 0){
        out[(size_t)i*2+0] = -1.2f*tanhf(o0 + b2[0]);
        out[(size_t)i*2+1] = -1.2f*tanhf(o1 + b2[1]);
    }
}

extern "C" void kernel_launch(void* const* d_in, const int* in_sizes, int n_in,
                              void* d_out, int out_size, void* d_ws, size_t ws_size,
                              hipStream_t stream){
    float* out = (float*)d_out;
    int fill_blocks = (out_size + 255) / 256;

    if (n_in != 14){
        fill_k<<<fill_blocks, 256, 0, stream>>>(out, out_size, 0.25f);
        return;
    }
    const int exp_sizes[14] = {300000, 1600000, 800000, 800000, 384, 64, 128, 64,
                               81920, 1280, 8192, 128, 256, 2};
    bool sizes_ok = (out_size == 100000);
    for (int i=0;i<14;i++) if (in_sizes[i] != exp_sizes[i]) sizes_ok = false;
    if (!sizes_ok){
        fill_k<<<fill_blocks, 256, 0, stream>>>(out, out_size, 0.5f);
        return;
    }

    // ---- ws layout, ~250.1 MB ----
    size_t need = 0;
    size_t o_flags = need; need += 16;
    size_t o_rs   = need; need += (size_t)NP*4;
    size_t o_cur  = need; need += (size_t)NP*4;
    size_t o_bsum = need; need += (size_t)NBLK*4;
    size_t o_boff = need; need += (size_t)NBLK*4;
    size_t o_Weh  = need; need += 384ull*4;
    size_t o_beh  = need; need += 64ull*4;
    size_t o_Wee  = need; need += 128ull*4;
    size_t o_bee  = need; need += 64ull*4;
    size_t o_Wl   = need; need += 81920ull*4;
    size_t o_bl   = need; need += 1280ull*4;
    size_t o_W1   = need; need += 8192ull*4;
    size_t o_b1   = need; need += 128ull*4;
    size_t o_W2   = need; need += 256ull*4;
    size_t o_b2   = need; need += 2ull*4;
    need = (need + 255) & ~(size_t)255;
    size_t o_perm = need; need += (size_t)NE*4;
    size_t o_srcp = need; need += (size_t)NE*4;
    size_t o_h    = need; need += (size_t)NN*64*4;
    size_t o_Bh   = need; need += (size_t)NN*64*4;
    size_t o_Eh   = need; need += (size_t)NN*64*4;
    size_t o_e    = need; need += (size_t)NE*64*4;
    if (ws_size < need){
        fill_k<<<fill_blocks, 256, 0, stream>>>(out, out_size, 0.75f);
        return;
    }

    char* p = (char*)d_ws;
    int*   flags = (int*)(p + o_flags);
    int*   row_start = (int*)(p + o_rs);
    int*   cursor    = (int*)(p + o_cur);
    int*   bsum = (int*)(p + o_bsum);
    int*   boff = (int*)(p + o_boff);
    float* Weh = (float*)(p + o_Weh);
    float* beh = (float*)(p + o_beh);
    float* Wee = (float*)(p + o_Wee);
    float* bee = (float*)(p + o_bee);
    float* Wlc = (float*)(p + o_Wl);
    float* blc = (float*)(p + o_bl);
    float* W1c = (float*)(p + o_W1);
    float* b1c = (float*)(p + o_b1);
    float* W2c = (float*)(p + o_W2);
    float* b2c = (float*)(p + o_b2);
    int*   perm = (int*)(p + o_perm);
    int*   srcp = (int*)(p + o_srcp);
    float* h  = (float*)(p + o_h);
    float* Bh = (float*)(p + o_Bh);
    float* Eh = (float*)(p + o_Eh);
    float* e  = (float*)(p + o_e);
    int* cnt = cursor;

    const int* src = (const int*)d_in[2];
    const int* dst = (const int*)d_in[3];

    probe_f_k<<<1, 256, 0, stream>>>((const unsigned short*)d_in[0], flags);
    probe_i_k<<<1, 256, 0, stream>>>(dst, flags);

    cvt_k<<<2, 256, 0, stream>>>(d_in[4], Weh, 384, flags);
    cvt_k<<<1, 256, 0, stream>>>(d_in[5], beh, 64, flags);
    cvt_k<<<1, 256, 0, stream>>>(d_in[6], Wee, 128, flags);
    cvt_k<<<1, 256, 0, stream>>>(d_in[7], bee, 64, flags);
    cvt_k<<<(81920+255)/256, 256, 0, stream>>>(d_in[8], Wlc, 81920, flags);
    cvt_k<<<5, 256, 0, stream>>>(d_in[9], blc, 1280, flags);
    cvt_k<<<32, 256, 0, stream>>>(d_in[10], W1c, 8192, flags);
    cvt_k<<<1, 256, 0, stream>>>(d_in[11], b1c, 128, flags);
    cvt_k<<<1, 256, 0, stream>>>(d_in[12], W2c, 256, flags);
    cvt_k<<<1, 256, 0, stream>>>(d_in[13], b2c, 2, flags);

    embed_k<<<NN/4, 256, 0, stream>>>(d_in[0], Weh, beh, h, flags);

    zero_cnt_k<<<NBLK, 256, 0, stream>>>(cnt);
    hist_k<<<NE/256, 256, 0, stream>>>(dst, cnt, flags);
    scan1_k<<<NBLK, 256, 0, stream>>>(cnt, row_start, bsum);
    scan2_k<<<1, 256, 0, stream>>>(bsum, boff);
    scan3_k<<<NBLK, 256, 0, stream>>>(row_start, boff, cursor);
    scatter_k<<<NE/256, 256, 0, stream>>>(dst, cursor, perm, flags);
    permsrc_k<<<NE/256, 256, 0, stream>>>(src, perm, srcp, flags);

    einit_k<<<NE*64/256, 256, 0, stream>>>(d_in[1], Wee, bee, perm, e, flags);

    for (int l=0; l<4; l++){
        node2_k<<<NN/4, 256, 0, stream>>>(l, h, Wlc, blc, Bh, Eh);
        gather_k<<<NN/4, 256, 0, stream>>>(l, e, h, Bh, Eh, srcp, row_start,
                                           Wlc, blc);
    }
    head_k<<<NN/4, 256, 0, stream>>>(h, W1c, b1c, W2c, b2c, out);
}

// Round 16
// 3844.861 us; speedup vs baseline: 2.6623x; 2.6623x over previous
//
#include <hip/hip_runtime.h>
#include <hip/hip_bf16.h>
#include <hip/hip_fp16.h>

#define NN 50000
#define NE 800000
#define NP 50176          // 196*256 padded node count for scan
#define NBLK 196

__device__ __forceinline__ float us2f_bf16(unsigned short u){
    unsigned v = ((unsigned)u) << 16; float f; __builtin_memcpy(&f, &v, 4); return f;
}
__device__ __forceinline__ float us2f_f16(unsigned short u){
    __half h; __builtin_memcpy(&h, &u, 2); return __half2float(h);
}
// mode: 0=bf16, 1=f16, 2=fp32
__device__ __forceinline__ float ldf3(const void* p, size_t i, int mode){
    if (mode == 2) return ((const float*)p)[i];
    unsigned short u = ((const unsigned short*)p)[i];
    return (mode == 0) ? us2f_bf16(u) : us2f_f16(u);
}
__device__ __forceinline__ int ldi(const int* p, size_t j, int i64){
    return i64 ? p[2*j] : p[j];
}

// ---------------- sentinel fill (fp32 output) ----------------
__global__ void fill_k(float* __restrict__ out, int n, float cval){
    int i = blockIdx.x*256 + threadIdx.x;
    if (i < n) out[i] = cval;
}

// ---------------- probes (validated) ----------------
__global__ void probe_f_k(const unsigned short* __restrict__ hf, int* __restrict__ flags){
    __shared__ int cnt;
    if (threadIdx.x == 0) cnt = 0;
    __syncthreads();
    int c = 0;
    for (int idx = threadIdx.x; idx < 2048; idx += 256){
        int ex = (hf[2*idx] >> 7) & 0xFF;
        if (ex >= 118 && ex <= 131) c++;
    }
    atomicAdd(&cnt, c);
    __syncthreads();
    if (threadIdx.x == 0){
        int inb = cnt;
        int mode;
        if (inb >= 1536)      mode = 0;     // bf16
        else if (inb <= 205)  mode = 2;     // fp32
        else                  mode = 1;     // f16
        flags[0] = mode;
    }
}
__global__ void probe_i_k(const int* __restrict__ d, int* __restrict__ flags){
    __shared__ int nz;
    if (threadIdx.x == 0) nz = 0;
    __syncthreads();
    int c = 0;
    for (int idx = threadIdx.x; idx < 2048; idx += 256){
        if (d[2*idx + 1] != 0) c++;
    }
    atomicAdd(&nz, c);
    __syncthreads();
    if (threadIdx.x == 0) flags[1] = (nz < 100) ? 1 : 0;
}

// ---------------- weight conversion ----------------
__global__ void cvt_k(const void* __restrict__ src, float* __restrict__ dst, int n,
                      const int* __restrict__ flags){
    int m = flags[0];
    int i = blockIdx.x*256 + threadIdx.x;
    if (i < n) dst[i] = ldf3(src, i, m);
}

// ---------------- node embedding: wave per node (validated) ----------------
__global__ __launch_bounds__(256) void embed_k(const void* __restrict__ hf,
        const float* __restrict__ W, const float* __restrict__ b,
        float* __restrict__ h, const int* __restrict__ flags){
    int f = flags[0];
    int t = threadIdx.x, c = t & 63;
    int i = blockIdx.x*4 + (t >> 6);
    float a = b[c];
    #pragma unroll
    for (int k=0;k<6;k++) a += ldf3(hf, (size_t)i*6+k, f) * W[k*64+c];
    h[(size_t)i*64+c] = a;
}

// ---------------- CSR build (counting sort by dst, validated) ----------------
__global__ void zero_cnt_k(int* __restrict__ cnt){
    int i = blockIdx.x*256 + threadIdx.x;
    cnt[i] = 0;
}
__global__ void hist_k(const int* __restrict__ dst, int* __restrict__ cnt,
                       const int* __restrict__ flags){
    int i64 = flags[1];
    int j = blockIdx.x*256 + threadIdx.x;
    atomicAdd(&cnt[ldi(dst, j, i64)], 1);
}
__global__ void scan1_k(const int* __restrict__ cnt, int* __restrict__ row_start,
                        int* __restrict__ bsum){
    __shared__ int s[256];
    int t = threadIdx.x;
    int i = blockIdx.x*256 + t;
    int v = cnt[i];
    s[t] = v; __syncthreads();
    #pragma unroll
    for (int off=1; off<256; off<<=1){
        int add = (t>=off) ? s[t-off] : 0;
        __syncthreads();
        s[t] += add;
        __syncthreads();
    }
    row_start[i] = s[t] - v;
    if (t==255) bsum[blockIdx.x] = s[255];
}
__global__ void scan2_k(const int* __restrict__ bsum, int* __restrict__ boff){
    __shared__ int s[256];
    int t = threadIdx.x;
    int v = (t < NBLK) ? bsum[t] : 0;
    s[t] = v; __syncthreads();
    #pragma unroll
    for (int off=1; off<256; off<<=1){
        int add = (t>=off) ? s[t-off] : 0;
        __syncthreads();
        s[t] += add;
        __syncthreads();
    }
    if (t < NBLK) boff[t] = s[t] - v;
}
__global__ void scan3_k(int* __restrict__ row_start, const int* __restrict__ boff,
                        int* __restrict__ cursor){
    int i = blockIdx.x*256 + threadIdx.x;
    int x = row_start[i] + boff[blockIdx.x];
    row_start[i] = x;
    cursor[i] = x;
}
__global__ void scatter_k(const int* __restrict__ dst, int* __restrict__ cursor,
                          int* __restrict__ perm, const int* __restrict__ flags){
    int i64 = flags[1];
    int j = blockIdx.x*256 + threadIdx.x;
    int d = ldi(dst, j, i64);
    int p = atomicAdd(&cursor[d], 1);
    perm[p] = j;
}
// CSR-ordered src as u16 (node ids < 65536)
__global__ void permsrc_k(const int* __restrict__ src, const int* __restrict__ perm,
                          unsigned short* __restrict__ srcp, const int* __restrict__ flags){
    int i64 = flags[1];
    int p = blockIdx.x*256 + threadIdx.x;
    srcp[p] = (unsigned short)ldi(src, perm[p], i64);
}

// ---------------- e init in CSR order ----------------
__global__ void einit_k(const void* __restrict__ ef, const float* __restrict__ Wee,
                        const float* __restrict__ bee, const int* __restrict__ perm,
                        float* __restrict__ e, const int* __restrict__ flags){
    int f = flags[0];
    int tid = blockIdx.x*256 + threadIdx.x;
    int c = tid & 63, p = tid >> 6;
    int j = perm[p];
    float f0 = ldf3(ef, (size_t)j*2+0, f), f1 = ldf3(ef, (size_t)j*2+1, f);
    e[(size_t)p*64+c] = bee[c] + f0*Wee[c] + f1*Wee[64+c];
}

// ---------------- per-layer Bh, Eh tables: wave per node (validated) ----------
__global__ __launch_bounds__(256) void node2_k(int l, const float* __restrict__ h,
        const float* __restrict__ Wlc, const float* __restrict__ blc,
        float* __restrict__ Bh, float* __restrict__ Eh){
    int t = threadIdx.x, c = t & 63;
    int i = blockIdx.x*4 + (t >> 6);
    const float* WB = Wlc + (size_t)l*5*4096 + 4096;
    const float* WE = Wlc + (size_t)l*5*4096 + 3*4096;
    const float* bm = blc + (size_t)l*320;
    float hv = h[(size_t)i*64 + c];
    float bo = bm[64+c], eo = bm[192+c];
    #pragma unroll 8
    for (int k=0;k<64;k++){
        float hk = __shfl(hv, k);
        bo += hk * WB[k*64+c];
        eo += hk * WE[k*64+c];
    }
    Bh[(size_t)i*64+c] = bo;
    Eh[(size_t)i*64+c] = eo;
}

// ---------------- fused GEMM-gate-scatter-update: 8 nodes per block ----------
// Edges CSR-sorted by dst -> each block owns a contiguous edge range.
// e tiles + WC staged in LDS; wave computes 16-edge x 64-ch GEMM slice in
// registers; gate; num/den accumulated in LDS (block-local); h update fused.
__global__ __launch_bounds__(256) void gg_k(int l,
        float* __restrict__ e, float* __restrict__ h,
        const float* __restrict__ Bh, const float* __restrict__ Eh,
        const unsigned short* __restrict__ srcp,
        const int* __restrict__ row_start,
        const float* __restrict__ Wlc, const float* __restrict__ blc){
    __shared__ float WCs[4096];
    __shared__ float eT[4096];
    __shared__ float AhL[512], DhL[512], ndN[512], ndD[512];
    __shared__ int rsL[9];
    __shared__ unsigned char own[64];

    int t = threadIdx.x, c = t & 63, w = t >> 6;
    int i0 = blockIdx.x * 8;
    const float* WA = Wlc + (size_t)l*5*4096;
    const float* WD = WA + 2*4096;
    const float* WC = WA + 4*4096;
    const float* bm = blc + (size_t)l*320;

    for (int idx=t; idx<4096; idx+=256) WCs[idx] = WC[idx];
    for (int idx=t; idx<512;  idx+=256){ ndN[idx]=0.0f; ndD[idx]=0.0f; }
    if (t < 9) rsL[t] = row_start[i0 + t];

    // Ah, Dh rows for the 8 nodes (wave w -> nodes w, w+4), R13-style shfl GEMV
    #pragma unroll
    for (int rep=0; rep<2; rep++){
        int n = w + rep*4;
        float hv = h[(size_t)(i0+n)*64 + c];
        float ah = bm[c], dh = bm[128+c];
        #pragma unroll 8
        for (int k=0;k<64;k++){
            float hk = __shfl(hv, k);
            ah += hk * WA[k*64+c];
            dh += hk * WD[k*64+c];
        }
        AhL[n*64+c] = ah;
        DhL[n*64+c] = dh;
    }
    __syncthreads();

    int p0 = rsL[0], pend = rsL[8];
    float bC = bm[256+c];

    for (int pt = p0; pt < pend; pt += 64){
        int nv = pend - pt; if (nv > 64) nv = 64;
        // load e tile (coalesced float4) + owner map
        for (int idx=t; idx<nv*16; idx+=256)
            ((float4*)eT)[idx] = ((const float4*)(e + (size_t)pt*64))[idx];
        if (t < 64){
            int nn = 0;
            if (t < nv){
                int p = pt + t;
                while (nn < 7 && p >= rsL[nn+1]) nn++;
            }
            own[t] = (unsigned char)nn;
        }
        __syncthreads();

        // 16-edge x 64-ch GEMM slice per wave: eT b128 broadcasts x WCs scalars
        float ce[16];
        #pragma unroll
        for (int q=0;q<16;q++) ce[q] = 0.0f;
        #pragma unroll 4
        for (int kq=0; kq<16; kq++){
            float w0 = WCs[(kq*4+0)*64+c];
            float w1 = WCs[(kq*4+1)*64+c];
            float w2 = WCs[(kq*4+2)*64+c];
            float w3 = WCs[(kq*4+3)*64+c];
            #pragma unroll
            for (int q=0;q<16;q++){
                float4 v = *(const float4*)&eT[(w*16+q)*64 + kq*4];
                ce[q] = fmaf(v.w, w3, fmaf(v.z, w2, fmaf(v.y, w1, fmaf(v.x, w0, ce[q]))));
            }
        }
        // gate + LDS num/den + e write
        #pragma unroll 1
        for (int q=0;q<16;q++){
            int lq = w*16+q;
            if (lq < nv){
                int p = pt + lq;
                int n = own[lq];
                int s = srcp[p];
                float ehat = ce[q] + bC + DhL[n*64+c] + Eh[(size_t)s*64+c];
                float sig = 1.0f/(1.0f + __expf(-ehat));
                atomicAdd(&ndN[n*64+c], sig * Bh[(size_t)s*64+c]);
                atomicAdd(&ndD[n*64+c], sig);
                e[(size_t)p*64+c] = eT[lq*64+c] + fmaxf(ehat, 0.0f);
            }
        }
        __syncthreads();   // protect eT before next tile load; drain atomics
    }

    // fused h update for the block's 8 nodes
    #pragma unroll
    for (int rep=0; rep<2; rep++){
        int n = w + rep*4;
        float hv = h[(size_t)(i0+n)*64 + c];
        float val = AhL[n*64+c] + ndN[n*64+c]/(ndD[n*64+c] + 1e-6f);
        h[(size_t)(i0+n)*64 + c] = hv + fmaxf(val, 0.0f);
    }
}

// ---------------- MLP head: wave per node (validated) ----------------
__global__ __launch_bounds__(256) void head_k(const float* __restrict__ h,
        const float* __restrict__ W1, const float* __restrict__ b1,
        const float* __restrict__ W2, const float* __restrict__ b2,
        float* __restrict__ out){
    int t = threadIdx.x, c = t & 63;
    int i = blockIdx.x*4 + (t >> 6);
    float hv = h[(size_t)i*64 + c];
    float z0 = b1[c], z1 = b1[64+c];
    #pragma unroll 8
    for (int k=0;k<64;k++){
        float hk = __shfl(hv, k);
        z0 += hk * W1[k*128+c];
        z1 += hk * W1[k*128+64+c];
    }
    z0 = fmaxf(z0, 0.0f); z1 = fmaxf(z1, 0.0f);
    float o0 = z0*W2[c*2+0] + z1*W2[(64+c)*2+0];
    float o1 = z0*W2[c*2+1] + z1*W2[(64+c)*2+1];
    #pragma unroll
    for (int off=32; off; off>>=1){
        o0 += __shfl_xor(o0, off);
        o1 += __shfl_xor(o1, off);
    }
    if (c == 0){
        out[(size_t)i*2+0] = -1.2f*tanhf(o0 + b2[0]);
        out[(size_t)i*2+1] = -1.2f*tanhf(o1 + b2[1]);
    }
}

extern "C" void kernel_launch(void* const* d_in, const int* in_sizes, int n_in,
                              void* d_out, int out_size, void* d_ws, size_t ws_size,
                              hipStream_t stream){
    float* out = (float*)d_out;
    int fill_blocks = (out_size + 255) / 256;

    if (n_in != 14){
        fill_k<<<fill_blocks, 256, 0, stream>>>(out, out_size, 0.25f);
        return;
    }
    const int exp_sizes[14] = {300000, 1600000, 800000, 800000, 384, 64, 128, 64,
                               81920, 1280, 8192, 128, 256, 2};
    bool sizes_ok = (out_size == 100000);
    for (int i=0;i<14;i++) if (in_sizes[i] != exp_sizes[i]) sizes_ok = false;
    if (!sizes_ok){
        fill_k<<<fill_blocks, 256, 0, stream>>>(out, out_size, 0.5f);
        return;
    }

    // ---- ws layout, ~248.8 MB (<= 250.1 known-good) ----
    size_t need = 0;
    size_t o_flags = need; need += 16;
    size_t o_rs   = need; need += (size_t)NP*4;
    size_t o_cur  = need; need += (size_t)NP*4;
    size_t o_bsum = need; need += (size_t)NBLK*4;
    size_t o_boff = need; need += (size_t)NBLK*4;
    size_t o_Weh  = need; need += 384ull*4;
    size_t o_beh  = need; need += 64ull*4;
    size_t o_Wee  = need; need += 128ull*4;
    size_t o_bee  = need; need += 64ull*4;
    size_t o_Wl   = need; need += 81920ull*4;
    size_t o_bl   = need; need += 1280ull*4;
    size_t o_W1   = need; need += 8192ull*4;
    size_t o_b1   = need; need += 128ull*4;
    size_t o_W2   = need; need += 256ull*4;
    size_t o_b2   = need; need += 2ull*4;
    need = (need + 255) & ~(size_t)255;
    size_t o_perm = need; need += (size_t)NE*4;
    size_t o_srcp = need; need += (size_t)NE*2;
    need = (need + 255) & ~(size_t)255;
    size_t o_h    = need; need += (size_t)NN*64*4;
    size_t o_Bh   = need; need += (size_t)NN*64*4;
    size_t o_Eh   = need; need += (size_t)NN*64*4;
    size_t o_e    = need; need += (size_t)NE*64*4;
    if (ws_size < need){
        fill_k<<<fill_blocks, 256, 0, stream>>>(out, out_size, 0.75f);
        return;
    }

    char* p = (char*)d_ws;
    int*   flags = (int*)(p + o_flags);
    int*   row_start = (int*)(p + o_rs);
    int*   cursor    = (int*)(p + o_cur);
    int*   bsum = (int*)(p + o_bsum);
    int*   boff = (int*)(p + o_boff);
    float* Weh = (float*)(p + o_Weh);
    float* beh = (float*)(p + o_beh);
    float* Wee = (float*)(p + o_Wee);
    float* bee = (float*)(p + o_bee);
    float* Wlc = (float*)(p + o_Wl);
    float* blc = (float*)(p + o_bl);
    float* W1c = (float*)(p + o_W1);
    float* b1c = (float*)(p + o_b1);
    float* W2c = (float*)(p + o_W2);
    float* b2c = (float*)(p + o_b2);
    int*   perm = (int*)(p + o_perm);
    unsigned short* srcp = (unsigned short*)(p + o_srcp);
    float* h  = (float*)(p + o_h);
    float* Bh = (float*)(p + o_Bh);
    float* Eh = (float*)(p + o_Eh);
    float* e  = (float*)(p + o_e);
    int* cnt = cursor;

    const int* src = (const int*)d_in[2];
    const int* dst = (const int*)d_in[3];

    probe_f_k<<<1, 256, 0, stream>>>((const unsigned short*)d_in[0], flags);
    probe_i_k<<<1, 256, 0, stream>>>(dst, flags);

    cvt_k<<<2, 256, 0, stream>>>(d_in[4], Weh, 384, flags);
    cvt_k<<<1, 256, 0, stream>>>(d_in[5], beh, 64, flags);
    cvt_k<<<1, 256, 0, stream>>>(d_in[6], Wee, 128, flags);
    cvt_k<<<1, 256, 0, stream>>>(d_in[7], bee, 64, flags);
    cvt_k<<<(81920+255)/256, 256, 0, stream>>>(d_in[8], Wlc, 81920, flags);
    cvt_k<<<5, 256, 0, stream>>>(d_in[9], blc, 1280, flags);
    cvt_k<<<32, 256, 0, stream>>>(d_in[10], W1c, 8192, flags);
    cvt_k<<<1, 256, 0, stream>>>(d_in[11], b1c, 128, flags);
    cvt_k<<<1, 256, 0, stream>>>(d_in[12], W2c, 256, flags);
    cvt_k<<<1, 256, 0, stream>>>(d_in[13], b2c, 2, flags);

    embed_k<<<NN/4, 256, 0, stream>>>(d_in[0], Weh, beh, h, flags);

    zero_cnt_k<<<NBLK, 256, 0, stream>>>(cnt);
    hist_k<<<NE/256, 256, 0, stream>>>(dst, cnt, flags);
    scan1_k<<<NBLK, 256, 0, stream>>>(cnt, row_start, bsum);
    scan2_k<<<1, 256, 0, stream>>>(bsum, boff);
    scan3_k<<<NBLK, 256, 0, stream>>>(row_start, boff, cursor);
    scatter_k<<<NE/256, 256, 0, stream>>>(dst, cursor, perm, flags);
    permsrc_k<<<NE/256, 256, 0, stream>>>(src, perm, srcp, flags);

    einit_k<<<NE*64/256, 256, 0, stream>>>(d_in[1], Wee, bee, perm, e, flags);

    for (int l=0; l<4; l++){
        node2_k<<<NN/4, 256, 0, stream>>>(l, h, Wlc, blc, Bh, Eh);
        gg_k<<<NN/8, 256, 0, stream>>>(l, e, h, Bh, Eh, srcp, row_start, Wlc, blc);
    }
    head_k<<<NN/4, 256, 0, stream>>>(h, W1c, b1c, W2c, b2c, out);
}

// Round 17
// 3575.670 us; speedup vs baseline: 2.8627x; 1.0753x over previous
//
#include <hip/hip_runtime.h>
#include <hip/hip_bf16.h>
#include <hip/hip_fp16.h>

#define NN 50000
#define NE 800000
#define NP 50176          // 196*256 padded node count for scan
#define NBLK 196

__device__ __forceinline__ float us2f_bf16(unsigned short u){
    unsigned v = ((unsigned)u) << 16; float f; __builtin_memcpy(&f, &v, 4); return f;
}
__device__ __forceinline__ float us2f_f16(unsigned short u){
    __half h; __builtin_memcpy(&h, &u, 2); return __half2float(h);
}
// mode: 0=bf16, 1=f16, 2=fp32
__device__ __forceinline__ float ldf3(const void* p, size_t i, int mode){
    if (mode == 2) return ((const float*)p)[i];
    unsigned short u = ((const unsigned short*)p)[i];
    return (mode == 0) ? us2f_bf16(u) : us2f_f16(u);
}
__device__ __forceinline__ int ldi(const int* p, size_t j, int i64){
    return i64 ? p[2*j] : p[j];
}

// ---------------- sentinel fill (fp32 output) ----------------
__global__ void fill_k(float* __restrict__ out, int n, float cval){
    int i = blockIdx.x*256 + threadIdx.x;
    if (i < n) out[i] = cval;
}

// ---------------- probes (validated) ----------------
__global__ void probe_f_k(const unsigned short* __restrict__ hf, int* __restrict__ flags){
    __shared__ int cnt;
    if (threadIdx.x == 0) cnt = 0;
    __syncthreads();
    int c = 0;
    for (int idx = threadIdx.x; idx < 2048; idx += 256){
        int ex = (hf[2*idx] >> 7) & 0xFF;
        if (ex >= 118 && ex <= 131) c++;
    }
    atomicAdd(&cnt, c);
    __syncthreads();
    if (threadIdx.x == 0){
        int inb = cnt;
        int mode;
        if (inb >= 1536)      mode = 0;     // bf16
        else if (inb <= 205)  mode = 2;     // fp32
        else                  mode = 1;     // f16
        flags[0] = mode;
    }
}
__global__ void probe_i_k(const int* __restrict__ d, int* __restrict__ flags){
    __shared__ int nz;
    if (threadIdx.x == 0) nz = 0;
    __syncthreads();
    int c = 0;
    for (int idx = threadIdx.x; idx < 2048; idx += 256){
        if (d[2*idx + 1] != 0) c++;
    }
    atomicAdd(&nz, c);
    __syncthreads();
    if (threadIdx.x == 0) flags[1] = (nz < 100) ? 1 : 0;
}

// ---------------- weight conversion ----------------
__global__ void cvt_k(const void* __restrict__ src, float* __restrict__ dst, int n,
                      const int* __restrict__ flags){
    int m = flags[0];
    int i = blockIdx.x*256 + threadIdx.x;
    if (i < n) dst[i] = ldf3(src, i, m);
}

// ---------------- node embedding: wave per node (validated) ----------------
__global__ __launch_bounds__(256) void embed_k(const void* __restrict__ hf,
        const float* __restrict__ W, const float* __restrict__ b,
        float* __restrict__ h, const int* __restrict__ flags){
    int f = flags[0];
    int t = threadIdx.x, c = t & 63;
    int i = blockIdx.x*4 + (t >> 6);
    float a = b[c];
    #pragma unroll
    for (int k=0;k<6;k++) a += ldf3(hf, (size_t)i*6+k, f) * W[k*64+c];
    h[(size_t)i*64+c] = a;
}

// ---------------- CSR build (counting sort by dst, validated) ----------------
__global__ void zero_cnt_k(int* __restrict__ cnt){
    int i = blockIdx.x*256 + threadIdx.x;
    cnt[i] = 0;
}
__global__ void hist_k(const int* __restrict__ dst, int* __restrict__ cnt,
                       const int* __restrict__ flags){
    int i64 = flags[1];
    int j = blockIdx.x*256 + threadIdx.x;
    atomicAdd(&cnt[ldi(dst, j, i64)], 1);
}
__global__ void scan1_k(const int* __restrict__ cnt, int* __restrict__ row_start,
                        int* __restrict__ bsum){
    __shared__ int s[256];
    int t = threadIdx.x;
    int i = blockIdx.x*256 + t;
    int v = cnt[i];
    s[t] = v; __syncthreads();
    #pragma unroll
    for (int off=1; off<256; off<<=1){
        int add = (t>=off) ? s[t-off] : 0;
        __syncthreads();
        s[t] += add;
        __syncthreads();
    }
    row_start[i] = s[t] - v;
    if (t==255) bsum[blockIdx.x] = s[255];
}
__global__ void scan2_k(const int* __restrict__ bsum, int* __restrict__ boff){
    __shared__ int s[256];
    int t = threadIdx.x;
    int v = (t < NBLK) ? bsum[t] : 0;
    s[t] = v; __syncthreads();
    #pragma unroll
    for (int off=1; off<256; off<<=1){
        int add = (t>=off) ? s[t-off] : 0;
        __syncthreads();
        s[t] += add;
        __syncthreads();
    }
    if (t < NBLK) boff[t] = s[t] - v;
}
__global__ void scan3_k(int* __restrict__ row_start, const int* __restrict__ boff,
                        int* __restrict__ cursor){
    int i = blockIdx.x*256 + threadIdx.x;
    int x = row_start[i] + boff[blockIdx.x];
    row_start[i] = x;
    cursor[i] = x;
}
__global__ void scatter_k(const int* __restrict__ dst, int* __restrict__ cursor,
                          int* __restrict__ perm, const int* __restrict__ flags){
    int i64 = flags[1];
    int j = blockIdx.x*256 + threadIdx.x;
    int d = ldi(dst, j, i64);
    int p = atomicAdd(&cursor[d], 1);
    perm[p] = j;
}
// CSR-ordered src as u16 (node ids < 65536)
__global__ void permsrc_k(const int* __restrict__ src, const int* __restrict__ perm,
                          unsigned short* __restrict__ srcp, const int* __restrict__ flags){
    int i64 = flags[1];
    int p = blockIdx.x*256 + threadIdx.x;
    srcp[p] = (unsigned short)ldi(src, perm[p], i64);
}

// ---------------- e init in CSR order ----------------
__global__ void einit_k(const void* __restrict__ ef, const float* __restrict__ Wee,
                        const float* __restrict__ bee, const int* __restrict__ perm,
                        float* __restrict__ e, const int* __restrict__ flags){
    int f = flags[0];
    int tid = blockIdx.x*256 + threadIdx.x;
    int c = tid & 63, p = tid >> 6;
    int j = perm[p];
    float f0 = ldf3(ef, (size_t)j*2+0, f), f1 = ldf3(ef, (size_t)j*2+1, f);
    e[(size_t)p*64+c] = bee[c] + f0*Wee[c] + f1*Wee[64+c];
}

// ---------------- per-layer Bh, Eh tables: wave per node (validated) ----------
__global__ __launch_bounds__(256) void node2_k(int l, const float* __restrict__ h,
        const float* __restrict__ Wlc, const float* __restrict__ blc,
        float* __restrict__ Bh, float* __restrict__ Eh){
    int t = threadIdx.x, c = t & 63;
    int i = blockIdx.x*4 + (t >> 6);
    const float* WB = Wlc + (size_t)l*5*4096 + 4096;
    const float* WE = Wlc + (size_t)l*5*4096 + 3*4096;
    const float* bm = blc + (size_t)l*320;
    float hv = h[(size_t)i*64 + c];
    float bo = bm[64+c], eo = bm[192+c];
    #pragma unroll 8
    for (int k=0;k<64;k++){
        float hk = __shfl(hv, k);
        bo += hk * WB[k*64+c];
        eo += hk * WE[k*64+c];
    }
    Bh[(size_t)i*64+c] = bo;
    Eh[(size_t)i*64+c] = eo;
}

// ---------------- fused GEMM-gate-scatter-update: 8 nodes per block ----------
// Per-wave 8-edge tiles in private LDS slices -> no per-tile barriers.
// Gate-phase Eh/Bh gathers hoisted so 16 loads are in flight together.
// num/den in LDS (block-local atomics); h update fused after one barrier.
__global__ __launch_bounds__(256) void gg_k(int l,
        float* __restrict__ e, float* __restrict__ h,
        const float* __restrict__ Bh, const float* __restrict__ Eh,
        const unsigned short* __restrict__ srcp,
        const int* __restrict__ row_start,
        const float* __restrict__ Wlc, const float* __restrict__ blc){
    __shared__ float WCs[4096];
    __shared__ float eT[4][512];          // 8 edges x 64 floats per wave
    __shared__ float AhL[512], DhL[512], ndN[512], ndD[512];
    __shared__ int rsL[9];

    int t = threadIdx.x, c = t & 63, w = t >> 6;
    int i0 = blockIdx.x * 8;
    const float* WA = Wlc + (size_t)l*5*4096;
    const float* WD = WA + 2*4096;
    const float* WC = WA + 4*4096;
    const float* bm = blc + (size_t)l*320;

    for (int idx=t; idx<4096; idx+=256) WCs[idx] = WC[idx];
    for (int idx=t; idx<512;  idx+=256){ ndN[idx]=0.0f; ndD[idx]=0.0f; }
    if (t < 9) rsL[t] = row_start[i0 + t];

    // Ah, Dh rows for the 8 nodes (wave w -> nodes w, w+4)
    #pragma unroll
    for (int rep=0; rep<2; rep++){
        int n = w + rep*4;
        float hv = h[(size_t)(i0+n)*64 + c];
        float ah = bm[c], dh = bm[128+c];
        #pragma unroll 8
        for (int k=0;k<64;k++){
            float hk = __shfl(hv, k);
            ah += hk * WA[k*64+c];
            dh += hk * WD[k*64+c];
        }
        AhL[n*64+c] = ah;
        DhL[n*64+c] = dh;
    }
    __syncthreads();

    int p0 = rsL[0], pend = rsL[8];
    float bC = bm[256+c];
    float* myT = eT[w];

    // wave-private tiles: wave w owns edges [p0+w*8 + 32k, +8)
    for (int pt = p0 + w*8; pt < pend; pt += 32){
        int nv = pend - pt; if (nv > 8) nv = 8;
        int cnt4 = nv * 16;                       // float4s in this tile
        const float4* gp = (const float4*)(e + (size_t)pt*64);
        if (c < cnt4)      ((float4*)myT)[c]      = gp[c];
        if (c+64 < cnt4)   ((float4*)myT)[c+64]   = gp[c+64];
        // same-wave LDS write->read: compiler inserts lgkmcnt waits, no barrier

        // hoisted gate-phase gathers (16 loads in flight)
        int sA[8];
        #pragma unroll
        for (int q=0;q<8;q++) sA[q] = (q < nv) ? (int)srcp[pt+q] : (int)srcp[p0];
        float ehv[8], bhv[8];
        #pragma unroll
        for (int q=0;q<8;q++) ehv[q] = Eh[(size_t)sA[q]*64 + c];
        #pragma unroll
        for (int q=0;q<8;q++) bhv[q] = Bh[(size_t)sA[q]*64 + c];

        // 8-edge x 64-ch GEMM slice: eT b128 broadcasts x WCs scalars
        float ce[8];
        #pragma unroll
        for (int q=0;q<8;q++) ce[q] = 0.0f;
        #pragma unroll 4
        for (int kq=0; kq<16; kq++){
            float w0 = WCs[(kq*4+0)*64+c];
            float w1 = WCs[(kq*4+1)*64+c];
            float w2 = WCs[(kq*4+2)*64+c];
            float w3 = WCs[(kq*4+3)*64+c];
            #pragma unroll
            for (int q=0;q<8;q++){
                float4 v = *(const float4*)&myT[q*64 + kq*4];
                ce[q] = fmaf(v.w, w3, fmaf(v.z, w2, fmaf(v.y, w1, fmaf(v.x, w0, ce[q]))));
            }
        }
        // gate + LDS num/den + e write
        #pragma unroll
        for (int q=0;q<8;q++){
            if (q < nv){
                int p = pt + q;
                int n = 0;
                while (n < 7 && p >= rsL[n+1]) n++;
                float ehat = ce[q] + bC + DhL[n*64+c] + ehv[q];
                float sig = 1.0f/(1.0f + __expf(-ehat));
                atomicAdd(&ndN[n*64+c], sig * bhv[q]);
                atomicAdd(&ndD[n*64+c], sig);
                e[(size_t)p*64+c] = myT[q*64+c] + fmaxf(ehat, 0.0f);
            }
        }
    }
    __syncthreads();   // drain all waves' LDS atomics

    // fused h update for the block's 8 nodes
    #pragma unroll
    for (int rep=0; rep<2; rep++){
        int n = w + rep*4;
        float hv = h[(size_t)(i0+n)*64 + c];
        float val = AhL[n*64+c] + ndN[n*64+c]/(ndD[n*64+c] + 1e-6f);
        h[(size_t)(i0+n)*64 + c] = hv + fmaxf(val, 0.0f);
    }
}

// ---------------- MLP head: wave per node (validated) ----------------
__global__ __launch_bounds__(256) void head_k(const float* __restrict__ h,
        const float* __restrict__ W1, const float* __restrict__ b1,
        const float* __restrict__ W2, const float* __restrict__ b2,
        float* __restrict__ out){
    int t = threadIdx.x, c = t & 63;
    int i = blockIdx.x*4 + (t >> 6);
    float hv = h[(size_t)i*64 + c];
    float z0 = b1[c], z1 = b1[64+c];
    #pragma unroll 8
    for (int k=0;k<64;k++){
        float hk = __shfl(hv, k);
        z0 += hk * W1[k*128+c];
        z1 += hk * W1[k*128+64+c];
    }
    z0 = fmaxf(z0, 0.0f); z1 = fmaxf(z1, 0.0f);
    float o0 = z0*W2[c*2+0] + z1*W2[(64+c)*2+0];
    float o1 = z0*W2[c*2+1] + z1*W2[(64+c)*2+1];
    #pragma unroll
    for (int off=32; off; off>>=1){
        o0 += __shfl_xor(o0, off);
        o1 += __shfl_xor(o1, off);
    }
    if (c == 0){
        out[(size_t)i*2+0] = -1.2f*tanhf(o0 + b2[0]);
        out[(size_t)i*2+1] = -1.2f*tanhf(o1 + b2[1]);
    }
}

extern "C" void kernel_launch(void* const* d_in, const int* in_sizes, int n_in,
                              void* d_out, int out_size, void* d_ws, size_t ws_size,
                              hipStream_t stream){
    float* out = (float*)d_out;
    int fill_blocks = (out_size + 255) / 256;

    if (n_in != 14){
        fill_k<<<fill_blocks, 256, 0, stream>>>(out, out_size, 0.25f);
        return;
    }
    const int exp_sizes[14] = {300000, 1600000, 800000, 800000, 384, 64, 128, 64,
                               81920, 1280, 8192, 128, 256, 2};
    bool sizes_ok = (out_size == 100000);
    for (int i=0;i<14;i++) if (in_sizes[i] != exp_sizes[i]) sizes_ok = false;
    if (!sizes_ok){
        fill_k<<<fill_blocks, 256, 0, stream>>>(out, out_size, 0.5f);
        return;
    }

    // ---- ws layout, ~248.8 MB (<= 250.1 known-good) ----
    size_t need = 0;
    size_t o_flags = need; need += 16;
    size_t o_rs   = need; need += (size_t)NP*4;
    size_t o_cur  = need; need += (size_t)NP*4;
    size_t o_bsum = need; need += (size_t)NBLK*4;
    size_t o_boff = need; need += (size_t)NBLK*4;
    size_t o_Weh  = need; need += 384ull*4;
    size_t o_beh  = need; need += 64ull*4;
    size_t o_Wee  = need; need += 128ull*4;
    size_t o_bee  = need; need += 64ull*4;
    size_t o_Wl   = need; need += 81920ull*4;
    size_t o_bl   = need; need += 1280ull*4;
    size_t o_W1   = need; need += 8192ull*4;
    size_t o_b1   = need; need += 128ull*4;
    size_t o_W2   = need; need += 256ull*4;
    size_t o_b2   = need; need += 2ull*4;
    need = (need + 255) & ~(size_t)255;
    size_t o_perm = need; need += (size_t)NE*4;
    size_t o_srcp = need; need += (size_t)NE*2;
    need = (need + 255) & ~(size_t)255;
    size_t o_h    = need; need += (size_t)NN*64*4;
    size_t o_Bh   = need; need += (size_t)NN*64*4;
    size_t o_Eh   = need; need += (size_t)NN*64*4;
    size_t o_e    = need; need += (size_t)NE*64*4;
    if (ws_size < need){
        fill_k<<<fill_blocks, 256, 0, stream>>>(out, out_size, 0.75f);
        return;
    }

    char* p = (char*)d_ws;
    int*   flags = (int*)(p + o_flags);
    int*   row_start = (int*)(p + o_rs);
    int*   cursor    = (int*)(p + o_cur);
    int*   bsum = (int*)(p + o_bsum);
    int*   boff = (int*)(p + o_boff);
    float* Weh = (float*)(p + o_Weh);
    float* beh = (float*)(p + o_beh);
    float* Wee = (float*)(p + o_Wee);
    float* bee = (float*)(p + o_bee);
    float* Wlc = (float*)(p + o_Wl);
    float* blc = (float*)(p + o_bl);
    float* W1c = (float*)(p + o_W1);
    float* b1c = (float*)(p + o_b1);
    float* W2c = (float*)(p + o_W2);
    float* b2c = (float*)(p + o_b2);
    int*   perm = (int*)(p + o_perm);
    unsigned short* srcp = (unsigned short*)(p + o_srcp);
    float* h  = (float*)(p + o_h);
    float* Bh = (float*)(p + o_Bh);
    float* Eh = (float*)(p + o_Eh);
    float* e  = (float*)(p + o_e);
    int* cnt = cursor;

    const int* src = (const int*)d_in[2];
    const int* dst = (const int*)d_in[3];

    probe_f_k<<<1, 256, 0, stream>>>((const unsigned short*)d_in[0], flags);
    probe_i_k<<<1, 256, 0, stream>>>(dst, flags);

    cvt_k<<<2, 256, 0, stream>>>(d_in[4], Weh, 384, flags);
    cvt_k<<<1, 256, 0, stream>>>(d_in[5], beh, 64, flags);
    cvt_k<<<1, 256, 0, stream>>>(d_in[6], Wee, 128, flags);
    cvt_k<<<1, 256, 0, stream>>>(d_in[7], bee, 64, flags);
    cvt_k<<<(81920+255)/256, 256, 0, stream>>>(d_in[8], Wlc, 81920, flags);
    cvt_k<<<5, 256, 0, stream>>>(d_in[9], blc, 1280, flags);
    cvt_k<<<32, 256, 0, stream>>>(d_in[10], W1c, 8192, flags);
    cvt_k<<<1, 256, 0, stream>>>(d_in[11], b1c, 128, flags);
    cvt_k<<<1, 256, 0, stream>>>(d_in[12], W2c, 256, flags);
    cvt_k<<<1, 256, 0, stream>>>(d_in[13], b2c, 2, flags);

    embed_k<<<NN/4, 256, 0, stream>>>(d_in[0], Weh, beh, h, flags);

    zero_cnt_k<<<NBLK, 256, 0, stream>>>(cnt);
    hist_k<<<NE/256, 256, 0, stream>>>(dst, cnt, flags);
    scan1_k<<<NBLK, 256, 0, stream>>>(cnt, row_start, bsum);
    scan2_k<<<1, 256, 0, stream>>>(bsum, boff);
    scan3_k<<<NBLK, 256, 0, stream>>>(row_start, boff, cursor);
    scatter_k<<<NE/256, 256, 0, stream>>>(dst, cursor, perm, flags);
    permsrc_k<<<NE/256, 256, 0, stream>>>(src, perm, srcp, flags);

    einit_k<<<NE*64/256, 256, 0, stream>>>(d_in[1], Wee, bee, perm, e, flags);

    for (int l=0; l<4; l++){
        node2_k<<<NN/4, 256, 0, stream>>>(l, h, Wlc, blc, Bh, Eh);
        gg_k<<<NN/8, 256, 0, stream>>>(l, e, h, Bh, Eh, srcp, row_start, Wlc, blc);
    }
    head_k<<<NN/4, 256, 0, stream>>>(h, W1c, b1c, W2c, b2c, out);
}